// Round 1
// baseline (927.426 us; speedup 1.0000x reference)
//
#include <hip/hip_runtime.h>
#include <hip/hip_bf16.h>

#define NEDGE 800000
#define NNODE 100000
#define LATD  128
#define NHEAD 4
#define WPAD  136            // padded LDS row length (halves): stride 272B -> conflict-free-ish column reads
#define TILES (NEDGE / 16)   // 50000, exact

typedef _Float16 half8 __attribute__((ext_vector_type(8)));
typedef float    f32x4 __attribute__((ext_vector_type(4)));

__device__ __forceinline__ half8 load_frag_f32(const float* __restrict__ p) {
    const f32x4 a = *reinterpret_cast<const f32x4*>(p);
    const f32x4 b = *reinterpret_cast<const f32x4*>(p + 4);
    half8 r;
    r[0] = (_Float16)a[0]; r[1] = (_Float16)a[1];
    r[2] = (_Float16)a[2]; r[3] = (_Float16)a[3];
    r[4] = (_Float16)b[0]; r[5] = (_Float16)b[1];
    r[6] = (_Float16)b[2]; r[7] = (_Float16)b[3];
    return r;
}

// Single fused pass over edges.
// Per 16-edge tile (one wave): q = gather(embeds,rows) @ Q, k = colEmb @ K, v = colEmb @ V
// att[e,h] = exp(clip(q.k)); atomicAdd attNorm[row,h]; atomicAdd out[row,:] += att*v
__global__ __launch_bounds__(512, 2) void edge_kernel(
    const int*   __restrict__ rows,
    const float* __restrict__ colEmb,
    const float* __restrict__ embeds,
    const float* __restrict__ Qw,
    const float* __restrict__ Kw,
    const float* __restrict__ Vw,
    float* __restrict__ outAcc,
    float* __restrict__ attNorm)
{
    extern __shared__ _Float16 lds[];
    _Float16* Qt = lds;                 // Qt[c][d] = Q[d][c] (transposed, fp16)
    _Float16* Kt = lds + LATD * WPAD;
    _Float16* Vt = lds + 2 * LATD * WPAD;

    const int t = threadIdx.x;
    // transpose-convert weights into LDS (one-time per block)
    for (int idx = t; idx < LATD * LATD; idx += 512) {
        const int d = idx >> 7, c = idx & 127;
        Qt[c * WPAD + d] = (_Float16)Qw[idx];
        Kt[c * WPAD + d] = (_Float16)Kw[idx];
        Vt[c * WPAD + d] = (_Float16)Vw[idx];
    }
    __syncthreads();

    const int lane = t & 63;
    const int c16  = lane & 15;   // A-row (edge-within-tile) for A frags; D-col for acc
    const int g    = lane >> 4;   // k-group
    const int wave = (blockIdx.x << 3) + (t >> 6);
    const int nw   = gridDim.x << 3;

    for (int tile = wave; tile < TILES; tile += nw) {
        const int e0 = tile << 4;
        const int eA = e0 + c16;
        const int rA = rows[eA];
        const float* xrow = embeds + (size_t)rA * LATD + g * 8;  // gathered row-embed
        const float* yrow = colEmb + (size_t)eA * LATD + g * 8;  // streamed col-embed

        half8 ay[4];
        f32x4 accQ[8] = {};
        f32x4 accK[8] = {};

        #pragma unroll
        for (int ks = 0; ks < 4; ++ks) {
            const int ko = ks * 32 + g * 8;
            const half8 ax = load_frag_f32(xrow + ks * 32);
            ay[ks] = load_frag_f32(yrow + ks * 32);
            #pragma unroll
            for (int nt = 0; nt < 8; ++nt) {
                const int rofs = (nt * 16 + c16) * WPAD + ko;
                const half8 bq = *reinterpret_cast<const half8*>(Qt + rofs);
                const half8 bk = *reinterpret_cast<const half8*>(Kt + rofs);
                accQ[nt] = __builtin_amdgcn_mfma_f32_16x16x32_f16(ax,     bq, accQ[nt], 0, 0, 0);
                accK[nt] = __builtin_amdgcn_mfma_f32_16x16x32_f16(ay[ks], bk, accK[nt], 0, 0, 0);
            }
        }

        // per-head dot: sum q*k over 32 cols = 2 acc tiles + lanes 0..15 butterfly
        f32x4 eh[4];
        #pragma unroll
        for (int h = 0; h < 4; ++h) {
            f32x4 p = accQ[2 * h] * accK[2 * h] + accQ[2 * h + 1] * accK[2 * h + 1];
            #pragma unroll
            for (int m = 1; m < 16; m <<= 1) {
                f32x4 q;
                q[0] = __shfl_xor(p[0], m);
                q[1] = __shfl_xor(p[1], m);
                q[2] = __shfl_xor(p[2], m);
                q[3] = __shfl_xor(p[3], m);
                p += q;
            }
            #pragma unroll
            for (int r = 0; r < 4; ++r)
                eh[h][r] = expf(fminf(10.0f, fmaxf(-10.0f, p[r])));
        }

        // rows for the 4 edges this lane owns in the D layout (row = g*4 + r)
        int rB[4];
        #pragma unroll
        for (int r = 0; r < 4; ++r) rB[r] = rows[e0 + g * 4 + r];

        // attNorm accumulation: lane c16==h handles head h (all 16 lanes hold identical eh)
        if (c16 < NHEAD) {
            const f32x4 sel = (c16 == 0) ? eh[0] : (c16 == 1) ? eh[1] : (c16 == 2) ? eh[2] : eh[3];
            #pragma unroll
            for (int r = 0; r < 4; ++r)
                atomicAdd(attNorm + rB[r] * NHEAD + c16, sel[r]);
        }

        // v matmul (reuses ay frags) + scale by expAtt + scatter
        f32x4 accV[8] = {};
        #pragma unroll
        for (int ks = 0; ks < 4; ++ks) {
            const int ko = ks * 32 + g * 8;
            #pragma unroll
            for (int nt = 0; nt < 8; ++nt) {
                const half8 bv = *reinterpret_cast<const half8*>(Vt + (nt * 16 + c16) * WPAD + ko);
                accV[nt] = __builtin_amdgcn_mfma_f32_16x16x32_f16(ay[ks], bv, accV[nt], 0, 0, 0);
            }
        }
        #pragma unroll
        for (int nt = 0; nt < 8; ++nt) {
            const f32x4 w = accV[nt] * eh[nt >> 1];
            #pragma unroll
            for (int r = 0; r < 4; ++r)
                atomicAdd(outAcc + (size_t)rB[r] * LATD + nt * 16 + c16, w[r]);
        }
    }
}

// out[n, j] /= (attNorm[n, j/32] + 1e-8)
__global__ void norm_kernel(float* __restrict__ out, const float* __restrict__ attNorm) {
    const int i = blockIdx.x * 256 + threadIdx.x;   // one float4 per thread
    if (i >= NNODE * 32) return;
    const int n = i >> 5;
    const int h = (i & 31) >> 3;
    const float s = attNorm[n * NHEAD + h] + 1e-8f;
    f32x4* p = reinterpret_cast<f32x4*>(out) + i;
    f32x4 v = *p;
    v[0] /= s; v[1] /= s; v[2] /= s; v[3] /= s;
    *p = v;
}

extern "C" void kernel_launch(void* const* d_in, const int* in_sizes, int n_in,
                              void* d_out, int out_size, void* d_ws, size_t ws_size,
                              hipStream_t stream) {
    const int*   rows   = (const int*)d_in[0];
    const float* colEmb = (const float*)d_in[1];
    const float* embeds = (const float*)d_in[2];
    const float* Qw     = (const float*)d_in[3];
    const float* Kw     = (const float*)d_in[4];
    const float* Vw     = (const float*)d_in[5];
    float* out     = (float*)d_out;
    float* attNorm = (float*)d_ws;   // NNODE * NHEAD floats = 1.6 MB

    hipMemsetAsync(out,     0, (size_t)NNODE * LATD  * sizeof(float), stream);
    hipMemsetAsync(attNorm, 0, (size_t)NNODE * NHEAD * sizeof(float), stream);

    const int ldsBytes = 3 * LATD * WPAD * sizeof(_Float16);  // 104448 B
    hipFuncSetAttribute((const void*)edge_kernel,
                        hipFuncAttributeMaxDynamicSharedMemorySize, ldsBytes);
    edge_kernel<<<512, 512, ldsBytes, stream>>>(rows, colEmb, embeds, Qw, Kw, Vw, out, attNorm);

    const int nVec = NNODE * 32;
    norm_kernel<<<(nVec + 255) / 256, 256, 0, stream>>>(out, attNorm);
}